// Round 7
// baseline (110.341 us; speedup 1.0000x reference)
//
#include <hip/hip_runtime.h>
#include <stdint.h>

// DualCompressor: y_fwd[v,m] = log(sum_k exp(d_out_t[v,k] + alpha_fwd[m,k]))
//                 y_bwd[v,m] = log(sum_k exp(d_in_t[v,k]  + alpha_bwd[m,k]))
// SIGMA = 1.0.   log(sum_k exp(phi_k)*exp(alpha_mk)).
//
// R7: coalesced staging via global_load_lds DMA (width=16) with a staging-side
// permutation so the per-row reads are conflict-even b128s from UNPADDED LDS.
//  - R5 (lane=row strided global loads): kernel ~14.2 us; ~4 us TA-scatter
//    over the 10.2 us HBM floor (64 lines/instr).
//  - R6 (manual LDS transpose): regressed to ~23 us: pad-65 broke 16B
//    alignment -> 128 ds_*_b32/wave + vmem round-trip + 8 waves/CU.
//  - Here: DMA straight to LDS (no VGPRs, no ds_writes), 1 KB/instr
//    coalesced. Chunk j (1 KB = rows 4j..4j+3), DMA dest slot = lane; lane
//    fetches global float4 f = 16*(lane>>4) + ((lane&15) - 4*(lane>>4) - j)&15.
//    Read (lane = row r): float4 c sits at slot 16*(r&3) + ((c+4*(r&3)+(r>>2))&15)
//    -> bank groups evenly 8 lanes/group (b128 baseline), e[] indices static.
//  - Alpha stays SGPR-resident (prep kernel -> exp(alpha) table, wave-uniform
//    indexing -> s_load + v_fmac with SGPR operand). No LDS for alpha.
//
// Block 128 = 2 waves (wave = compressor c) over the same 64 rows.
// LDS 2x16 KB = 32 KB -> 5 blocks/CU = 10 waves/CU; 160 KB DMA in flight/CU.
// Edge rows clamp the DMA source; stores guarded. No early return (barrier).

#define K_DIM 64

__global__ __launch_bounds__(256) void prep_ealpha_kernel(
    const float* __restrict__ alpha_fwd,
    const float* __restrict__ alpha_bwd,
    float* __restrict__ ea)
{
    int i = blockIdx.x * 256 + threadIdx.x;       // grid 8 -> i in 0..2047
    float a = (i < 1024) ? alpha_fwd[i] : alpha_bwd[i - 1024];
    ea[i] = __expf(a);
}

__global__ __launch_bounds__(128) void dual_compress_kernel(
    const float* __restrict__ d_out_t,
    const float* __restrict__ d_in_t,
    const float* __restrict__ ea,     // exp(alpha): [c][m][k], 2048 floats
    float* __restrict__ out, int V)
{
    __shared__ float stage[2][64 * K_DIM];        // 2 x 16 KB, no pad

    int tid  = threadIdx.x;
    int lane = tid & 63;
    int w    = tid >> 6;        // wave id = compressor c (0=fwd, 1=bwd)
    int c    = w;
    int rowbase = blockIdx.x * 64;
    const float* base = c ? d_in_t : d_out_t;
    float* st = stage[w];

    // ---- staging: 16 x 1KB chunks, DMA global -> LDS, permuted within chunk
    size_t chunk0 = (size_t)rowbase * K_DIM;
    size_t maxoff = (size_t)V * K_DIM - 4;        // last valid float4 start
    int rp = lane >> 4;                            // slot row r' = 0..3
    int oo = lane & 15;                            // slot col o = 0..15
    #pragma unroll
    for (int j = 0; j < 16; ++j) {
        int cg = (oo - 4 * rp - j) & 15;           // global col-chunk fetched
        size_t eoff = chunk0 + (size_t)j * 256 + (size_t)(rp * 64 + cg * 4);
        if (eoff > maxoff) eoff = maxoff;          // tail-block clamp
        auto* gp = reinterpret_cast<const float __attribute__((address_space(1)))*>(
            reinterpret_cast<uintptr_t>(base + eoff));
        auto* lp = reinterpret_cast<float __attribute__((address_space(3)))*>(
            reinterpret_cast<uintptr_t>(st + j * 256));
        __builtin_amdgcn_global_load_lds(gp, lp, 16, 0, 0);
    }
    __syncthreads();   // drains vmcnt(0): all DMA writes to LDS visible

    // ---- read own row (r = lane) with inverse swizzle, exp into regs
    int jr = lane >> 2;                            // chunk of my row
    int rr = lane & 3;                             // row within chunk
    const float* rbase = st + jr * 256 + rr * 64;
    int ph = (4 * rr + jr) & 15;
    float e[64];
    #pragma unroll
    for (int cc = 0; cc < 16; ++cc) {
        float4 q = *(const float4*)(rbase + (((cc + ph) & 15) << 2));
        e[4*cc+0] = __expf(q.x);
        e[4*cc+1] = __expf(q.y);
        e[4*cc+2] = __expf(q.z);
        e[4*cc+3] = __expf(q.w);
    }

    // ---- 1024 v_fmac with SGPR alpha operand (wave-uniform table base)
    const float* eac = ea + __builtin_amdgcn_readfirstlane(c << 10);

    float acc[16];
    #pragma unroll
    for (int mi = 0; mi < 16; ++mi) acc[mi] = 0.0f;

    #pragma unroll
    for (int kc = 0; kc < 16; ++kc) {
        #pragma unroll
        for (int mi = 0; mi < 16; ++mi) {
            const float* arow = eac + mi * K_DIM + kc * 4;
            acc[mi] = fmaf(e[kc*4+0], arow[0], acc[mi]);
            acc[mi] = fmaf(e[kc*4+1], arow[1], acc[mi]);
            acc[mi] = fmaf(e[kc*4+2], arow[2], acc[mi]);
            acc[mi] = fmaf(e[kc*4+3], arow[3], acc[mi]);
        }
    }

    // ---- logs + guarded store: y_fwd (V x 16) then y_bwd (V x 16)
    int v = rowbase + lane;
    if (v < V) {
        float* orow = out + ((size_t)c * V + v) * 16;
        #pragma unroll
        for (int i = 0; i < 4; ++i) {
            float4 y;
            y.x = __logf(acc[4*i+0]);
            y.y = __logf(acc[4*i+1]);
            y.z = __logf(acc[4*i+2]);
            y.w = __logf(acc[4*i+3]);
            ((float4*)orow)[i] = y;
        }
    }
}

extern "C" void kernel_launch(void* const* d_in, const int* in_sizes, int n_in,
                              void* d_out, int out_size, void* d_ws, size_t ws_size,
                              hipStream_t stream) {
    const float* d_out_t   = (const float*)d_in[0];
    const float* d_in_t    = (const float*)d_in[1];
    const float* alpha_fwd = (const float*)d_in[2];
    const float* alpha_bwd = (const float*)d_in[3];
    float* out = (float*)d_out;
    float* ea  = (float*)d_ws;            // 2048 floats of scratch

    int V = in_sizes[0] / K_DIM;          // 100000

    prep_ealpha_kernel<<<8, 256, 0, stream>>>(alpha_fwd, alpha_bwd, ea);

    int grid = (V + 63) / 64;             // 64 rows per block (both c's)
    dual_compress_kernel<<<grid, 128, 0, stream>>>(
        d_out_t, d_in_t, ea, out, V);
}